// Round 7
// baseline (1013.974 us; speedup 1.0000x reference)
//
#include <hip/hip_runtime.h>

typedef unsigned short u16;
typedef __attribute__((ext_vector_type(8))) short s8frag;   // 8 bf16 (4 VGPRs)
typedef __attribute__((ext_vector_type(4))) float f32x4;    // MFMA accumulator

#define GLOAD16(gp, lp)                                                        \
  __builtin_amdgcn_global_load_lds(                                            \
      (const __attribute__((address_space(1))) void*)(gp),                     \
      (__attribute__((address_space(3))) void*)(lp), 16, 0, 0)

__device__ __forceinline__ u16 f2bf(float x) {
  unsigned int u = __float_as_uint(x);
  unsigned int r = (u + 0x7fffu + ((u >> 16) & 1u)) >> 16;  // RNE
  return (u16)r;
}

// ---------------------------------------------------------------------------
// Kernel 1: fold BN into 1x1-conv weights (both branches in one launch).
// ---------------------------------------------------------------------------
__global__ __launch_bounds__(256) void prep_w(
    const float* __restrict__ wi, const float* __restrict__ bi,
    const float* __restrict__ gi, const float* __restrict__ bei,
    const float* __restrict__ mi, const float* __restrict__ vi,
    const float* __restrict__ wp, const float* __restrict__ bp,
    const float* __restrict__ gp, const float* __restrict__ bep,
    const float* __restrict__ mp, const float* __restrict__ vp,
    u16* __restrict__ wout_i, float* __restrict__ bias_i,
    u16* __restrict__ wout_p, float* __restrict__ bias_p) {
  int gidx = blockIdx.x * 256 + threadIdx.x;  // 0 .. 2*512*512-1
  int branch = gidx >> 18;
  int idx = gidx & ((1 << 18) - 1);
  int o = idx >> 9, c = idx & 511;
  const float* w = branch ? wp : wi;
  const float* b = branch ? bp : bi;
  const float* g = branch ? gp : gi;
  const float* be = branch ? bep : bei;
  const float* mn = branch ? mp : mi;
  const float* vr = branch ? vp : vi;
  u16* wo = branch ? wout_p : wout_i;
  float* bo = branch ? bias_p : bias_i;
  float scale = g[o] * rsqrtf(vr[o] + 1e-5f);
  wo[idx] = f2bf(w[idx] * scale);
  if (c == 0) bo[o] = scale * (b[o] - mn[o]) + be[o];
}

// ---------------------------------------------------------------------------
// Kernel 2: FULLY FUSED build+GEMM. No B intermediate in memory.
// Block = 128 hw-cols (fixed h, 128 consecutive w) x 128 out-ch (rt 0..3).
// Per K-step (32 ch): the block BUILDS its B-subtile (pts: direct transpose;
// img: 5-level upsample+pad gather-sum, offsets hoisted per thread) into the
// XOR-swizzled LDS layout; A staged via global_load_lds with the matching
// source swizzle (round-5 proven). 2 LDS buffers, ONE barrier per step
// (build writes go to buf^1 -> no overwrite hazard before the flip).
// XCD-chunked swizzle keeps the 4 rt of one col-tile back-to-back on one XCD
// -> rt-redundant input reads are L2-served.
// Grid: (4096, 1, 2 branches), block 256, LDS 32 KiB.
// ---------------------------------------------------------------------------
__global__ __launch_bounds__(256, 3) void gemm_all(
    const u16* __restrict__ Aimg, const u16* __restrict__ Apts,
    const float* __restrict__ f0, const float* __restrict__ f1,
    const float* __restrict__ f2, const float* __restrict__ f3,
    const float* __restrict__ f4, const float* __restrict__ ptsf,
    const float* __restrict__ biasImg, const float* __restrict__ biasPts,
    float* __restrict__ out) {
  int br = blockIdx.z;
  const u16* A = br ? Apts : Aimg;
  const float* bias = br ? biasPts : biasImg;

  // bijective XCD chunk swizzle: 4096 wgs, 8 XCDs, 512 per XCD; rt fastest
  int s = blockIdx.x;
  int w_ = (s & 7) * 512 + (s >> 3);
  int rt = w_ & 3;                     // row tile 0..3
  int ct = w_ >> 2;                    // col tile 0..1023
  int n = ct >> 9;                     // sample
  int cthw = ct & 511;
  int colbase = cthw * 128;            // hw base within sample
  int h = cthw >> 1;                   // fixed h for this block
  int w0 = (cthw & 1) * 128;           // w base

  __shared__ u16 As[2][128 * 32];      // 16 KiB
  __shared__ u16 Bs[2][128 * 32];      // 16 KiB

  int t = threadIdx.x;
  int wave = t >> 6, lane = t & 63;
  int wr = wave >> 1, wc = wave & 1;
  int lrow = lane & 15;
  int q = lane >> 4;                   // k-chunk 0..3

  // ---- build-thread mapping: px = B row (hw), cg = chunk group 0..1 ----
  int px = t & 127, cg = t >> 7;
  int wpx = w0 + px;

  const float* feats[5] = {f0, f1, f2, f3, f4};
  const int S[5] = {128, 64, 32, 16, 8};
  long gbase[5];
  if (br == 0) {
#pragma unroll
    for (int l = 0; l < 5; ++l) {
      int sl = S[l];
      int scale = (n == 1 && l > 0) ? 2 : 1;
      int u = sl * scale, pad = (256 - u) >> 1;
      int ih = h - pad; ih = ih < 0 ? 0 : (ih > u - 1 ? u - 1 : ih); ih /= scale;
      int iw = wpx - pad; iw = iw < 0 ? 0 : (iw > u - 1 ? u - 1 : iw); iw /= scale;
      gbase[l] = (long)(n * 512) * sl * sl + ih * sl + iw;
    }
  }
  long pbase = (long)(n * 512) * 65536 + h * 256 + wpx;

  // build B-subtile for K-step kt_ into buffer buf (chunks cg, cg+2)
#define BUILD(buf, kt_)                                                       \
  {                                                                           \
    int kk_ = (kt_) * 32;                                                     \
    _Pragma("unroll") for (int ci = 0; ci < 2; ++ci) {                        \
      int chunk = cg + ci * 2;                                                \
      int c0 = kk_ + chunk * 8;                                               \
      u16 pk[8];                                                              \
      if (br == 0) {                                                          \
        _Pragma("unroll") for (int j = 0; j < 8; ++j) {                       \
          int c = c0 + j;                                                     \
          float acc_ = 0.f;                                                   \
          _Pragma("unroll") for (int l = 0; l < 5; ++l)                       \
            acc_ += feats[l][gbase[l] + (long)c * (S[l] * S[l])];             \
          pk[j] = f2bf(acc_);                                                 \
        }                                                                     \
      } else {                                                                \
        _Pragma("unroll") for (int j = 0; j < 8; ++j)                         \
          pk[j] = f2bf(ptsf[pbase + (long)(c0 + j) * 65536]);                 \
      }                                                                       \
      int sw_ = chunk ^ ((px >> 1) & 3);                                      \
      *(uint4*)((char*)&Bs[buf][0] + px * 64 + sw_ * 16) = *(const uint4*)pk; \
    }                                                                         \
  }

  // A stage (round-5 proven: source-column swizzle, linear LDS dest)
#define ASTAGE(buf, kt_)                                                      \
  {                                                                           \
    int kk_ = (kt_) * 32;                                                     \
    _Pragma("unroll") for (int i = 0; i < 2; ++i) {                           \
      int slot = t + i * 256;                                                 \
      int row = slot >> 2, kp = slot & 3;                                     \
      int sw_ = (row >> 1) & 3;                                               \
      GLOAD16(A + ((long)(rt * 128 + row) * 512 + kk_ + ((kp ^ sw_) * 8)),    \
              &As[buf][slot * 8]);                                            \
    }                                                                         \
  }

  f32x4 acc[4][4] = {};

  // prologue: tile 0
  ASTAGE(0, 0);
  BUILD(0, 0);
  asm volatile("s_waitcnt vmcnt(0) lgkmcnt(0)" ::: "memory");
  __builtin_amdgcn_s_barrier();

#pragma unroll 1
  for (int kt = 0; kt < 16; ++kt) {
    int cur = kt & 1;
    // fragment reads of current buffer
    s8frag a[4], b[4];
#pragma unroll
    for (int m = 0; m < 4; ++m) {
      int r = wr * 64 + m * 16 + lrow;
      a[m] = *(const s8frag*)&As[cur][r * 32 + ((q ^ ((r >> 1) & 3)) * 8)];
    }
#pragma unroll
    for (int nn = 0; nn < 4; ++nn) {
      int r = wc * 64 + nn * 16 + lrow;
      b[nn] = *(const s8frag*)&Bs[cur][r * 32 + ((q ^ ((r >> 1) & 3)) * 8)];
    }
    // stage + build NEXT tile into buf^1 (overlaps MFMA below)
    if (kt < 15) {
      ASTAGE(cur ^ 1, kt + 1);
      BUILD(cur ^ 1, kt + 1);
    }
    __builtin_amdgcn_s_setprio(1);
#pragma unroll
    for (int m = 0; m < 4; ++m)
#pragma unroll
      for (int nn = 0; nn < 4; ++nn)
        acc[m][nn] =
            __builtin_amdgcn_mfma_f32_16x16x32_bf16(a[m], b[nn], acc[m][nn], 0, 0, 0);
    __builtin_amdgcn_s_setprio(0);
    if (kt < 15) {
      asm volatile("s_waitcnt vmcnt(0) lgkmcnt(0)" ::: "memory");
      __builtin_amdgcn_s_barrier();
    }
  }
#undef BUILD
#undef ASTAGE

  // epilogue: bias + relu, write fp32 NCHW with channel offset br*512
  long outbase = ((long)n * 1024 + br * 512) * 65536;
#pragma unroll
  for (int m = 0; m < 4; ++m) {
    int o0 = rt * 128 + wr * 64 + m * 16 + (lane >> 4) * 4;
#pragma unroll
    for (int nn = 0; nn < 4; ++nn) {
      int hw = colbase + wc * 64 + nn * 16 + (lane & 15);
#pragma unroll
      for (int j = 0; j < 4; ++j) {
        int o = o0 + j;
        float v = acc[m][nn][j] + bias[o];
        v = v > 0.f ? v : 0.f;
        out[outbase + (long)o * 65536 + hw] = v;
      }
    }
  }
}

// ---------------------------------------------------------------------------
extern "C" void kernel_launch(void* const* d_in, const int* in_sizes, int n_in,
                              void* d_out, int out_size, void* d_ws,
                              size_t ws_size, hipStream_t stream) {
  (void)in_sizes; (void)n_in; (void)out_size; (void)ws_size;
  const float* f0 = (const float*)d_in[0];
  const float* f1 = (const float*)d_in[1];
  const float* f2 = (const float*)d_in[2];
  const float* f3 = (const float*)d_in[3];
  const float* f4 = (const float*)d_in[4];
  const float* pts = (const float*)d_in[5];
  const float* img_w = (const float*)d_in[6];
  const float* img_b = (const float*)d_in[7];
  const float* img_gamma = (const float*)d_in[8];
  const float* img_beta = (const float*)d_in[9];
  const float* img_mean = (const float*)d_in[10];
  const float* img_var = (const float*)d_in[11];
  const float* pts_w = (const float*)d_in[12];
  const float* pts_b = (const float*)d_in[13];
  const float* pts_gamma = (const float*)d_in[14];
  const float* pts_beta = (const float*)d_in[15];
  const float* pts_mean = (const float*)d_in[16];
  const float* pts_var = (const float*)d_in[17];

  char* ws = (char*)d_ws;
  u16* wA_img = (u16*)ws;                          // 512 KiB
  u16* wA_pts = wA_img + 512 * 512;                // 512 KiB
  float* bias_img = (float*)(ws + (1u << 20));
  float* bias_pts = bias_img + 512;

  prep_w<<<2048, 256, 0, stream>>>(img_w, img_b, img_gamma, img_beta, img_mean,
                                   img_var, pts_w, pts_b, pts_gamma, pts_beta,
                                   pts_mean, pts_var, wA_img, bias_img, wA_pts,
                                   bias_pts);
  gemm_all<<<dim3(4096, 1, 2), 256, 0, stream>>>(
      wA_img, wA_pts, f0, f1, f2, f3, f4, pts, bias_img, bias_pts,
      (float*)d_out);
}

// Round 8
// 542.434 us; speedup vs baseline: 1.8693x; 1.8693x over previous
//
#include <hip/hip_runtime.h>

typedef unsigned short u16;
typedef __attribute__((ext_vector_type(8))) short s8frag;   // 8 bf16 (4 VGPRs)
typedef __attribute__((ext_vector_type(4))) float f32x4;    // MFMA accumulator

#define GLOAD16(gp, lp)                                                        \
  __builtin_amdgcn_global_load_lds(                                            \
      (const __attribute__((address_space(1))) void*)(gp),                     \
      (__attribute__((address_space(3))) void*)(lp), 16, 0, 0)

__device__ __forceinline__ u16 f2bf(float x) {
  unsigned int u = __float_as_uint(x);
  unsigned int r = (u + 0x7fffu + ((u >> 16) & 1u)) >> 16;  // RNE
  return (u16)r;
}

// ---------------------------------------------------------------------------
// Kernel 1: fold BN into 1x1-conv weights (both branches in one launch).
// ---------------------------------------------------------------------------
__global__ __launch_bounds__(256) void prep_w(
    const float* __restrict__ wi, const float* __restrict__ bi,
    const float* __restrict__ gi, const float* __restrict__ bei,
    const float* __restrict__ mi, const float* __restrict__ vi,
    const float* __restrict__ wp, const float* __restrict__ bp,
    const float* __restrict__ gp, const float* __restrict__ bep,
    const float* __restrict__ mp, const float* __restrict__ vp,
    u16* __restrict__ wout_i, float* __restrict__ bias_i,
    u16* __restrict__ wout_p, float* __restrict__ bias_p) {
  int gidx = blockIdx.x * 256 + threadIdx.x;  // 0 .. 2*512*512-1
  int branch = gidx >> 18;
  int idx = gidx & ((1 << 18) - 1);
  int o = idx >> 9, c = idx & 511;
  const float* w = branch ? wp : wi;
  const float* b = branch ? bp : bi;
  const float* g = branch ? gp : gi;
  const float* be = branch ? bep : bei;
  const float* mn = branch ? mp : mi;
  const float* vr = branch ? vp : vi;
  u16* wo = branch ? wout_p : wout_i;
  float* bo = branch ? bias_p : bias_i;
  float scale = g[o] * rsqrtf(vr[o] + 1e-5f);
  wo[idx] = f2bf(w[idx] * scale);
  if (c == 0) bo[o] = scale * (b[o] - mn[o]) + be[o];
}

// ---------------------------------------------------------------------------
// Kernel 2: img multi-level sum (upsample-by-(n+1) for lvl>0, edge-pad to 256)
// written TRANSPOSED as bf16:  dst[n][hw][c]
// ---------------------------------------------------------------------------
__global__ __launch_bounds__(256) void build_img_t(
    const float* __restrict__ f0, const float* __restrict__ f1,
    const float* __restrict__ f2, const float* __restrict__ f3,
    const float* __restrict__ f4, u16* __restrict__ dst) {
  __shared__ float tile[64][65];
  int t = threadIdx.x;
  int wblk = blockIdx.x;          // 0..3
  int h = blockIdx.y;             // 0..255
  int n = blockIdx.z >> 3;        // 0..1
  int cblk = blockIdx.z & 7;      // 0..7
  int wl = t & 63, w = wblk * 64 + wl;

  const float* feats[5] = {f0, f1, f2, f3, f4};
  const int S[5] = {128, 64, 32, 16, 8};
  int off[5];
#pragma unroll
  for (int l = 0; l < 5; ++l) {
    int s = S[l];
    int scale = (n == 1 && l > 0) ? 2 : 1;
    int u = s * scale, pad = (256 - u) >> 1;
    int ih = h - pad; ih = ih < 0 ? 0 : (ih > u - 1 ? u - 1 : ih); ih /= scale;
    int iw = w - pad; iw = iw < 0 ? 0 : (iw > u - 1 ? u - 1 : iw); iw /= scale;
    off[l] = ih * s + iw;
  }
  int cbase = cblk * 64;
  for (int cs = 0; cs < 16; ++cs) {
    int cl = cs * 4 + (t >> 6);
    int c = cbase + cl;
    float acc = 0.f;
#pragma unroll
    for (int l = 0; l < 5; ++l) {
      int s = S[l];
      acc += feats[l][(long)(n * 512 + c) * s * s + off[l]];
    }
    tile[cl][wl] = acc;
  }
  __syncthreads();
  long hwb = (long)h * 256 + wblk * 64;
#pragma unroll
  for (int half = 0; half < 2; ++half) {
    int c0 = (t & 7) * 8;
    int wl2 = half * 32 + (t >> 3);
    u16 p[8];
#pragma unroll
    for (int j = 0; j < 8; ++j) p[j] = f2bf(tile[c0 + j][wl2]);
    long di = ((long)n * 65536 + hwb + wl2) * 512 + cbase + c0;
    *(uint4*)(dst + di) = *(const uint4*)p;
  }
}

// ---------------------------------------------------------------------------
// Kernel 3: pts NCHW fp32 -> [n][hw][c] bf16 (transpose + convert)
// ---------------------------------------------------------------------------
__global__ __launch_bounds__(256) void build_pts_t(
    const float* __restrict__ src, u16* __restrict__ dst) {
  __shared__ float tile[64][65];
  int t = threadIdx.x;
  int wblk = blockIdx.x;
  int h = blockIdx.y;
  int n = blockIdx.z >> 3;
  int cblk = blockIdx.z & 7;
  int cbase = cblk * 64;
  int wq = t & 15;     // w-quad within 64
  int cl0 = t >> 4;    // 0..15
#pragma unroll
  for (int j = 0; j < 4; ++j) {
    int cl = cl0 + j * 16;
    int c = cbase + cl;
    float4 v = *(const float4*)&src[((long)(n * 512 + c) * 256 + h) * 256 +
                                    wblk * 64 + wq * 4];
    tile[cl][wq * 4 + 0] = v.x;
    tile[cl][wq * 4 + 1] = v.y;
    tile[cl][wq * 4 + 2] = v.z;
    tile[cl][wq * 4 + 3] = v.w;
  }
  __syncthreads();
  long hwb = (long)h * 256 + wblk * 64;
#pragma unroll
  for (int half = 0; half < 2; ++half) {
    int c0 = (t & 7) * 8;
    int wl2 = half * 32 + (t >> 3);
    u16 p[8];
#pragma unroll
    for (int j = 0; j < 8; ++j) p[j] = f2bf(tile[c0 + j][wl2]);
    long di = ((long)n * 65536 + hwb + wl2) * 512 + cbase + c0;
    *(uint4*)(dst + di) = *(const uint4*)p;
  }
}

// ---------------------------------------------------------------------------
// Kernel 4: bf16 MFMA GEMM, 128x128 tile, BK=32, 4 waves, acc 4x4.
// RING-4 DEEP PIPELINE: 4 LDS buffer pairs (64 KiB, 2 blocks/CU).
// At step kt: read buf kt&3, issue stage kt+3, MFMA, then vmcnt(8) retires
// stage kt+1 -- issued TWO steps ago (~3.2us of slack vs loaded latency),
// so the barrier never waits on fresh loads. ONE barrier per step.
// (Rounds 3/5 depth-2 was null because slack was ~0; this is the depth fix.)
// LDS XOR swizzle (round-5 proven): linear LDS dest, source column chunk
// kp^((row>>1)&3), read chunk q^((r>>1)&3) -> conflict-free ds_read_b128.
// XCD-chunked swizzle: 4 rt of one col-tile back-to-back on one XCD.
// ---------------------------------------------------------------------------
__global__ __launch_bounds__(256, 2) void gemm_fused(
    const u16* __restrict__ Aimg, const u16* __restrict__ Apts,
    const u16* __restrict__ Bimg, const u16* __restrict__ Bpts,
    const float* __restrict__ biasImg, const float* __restrict__ biasPts,
    float* __restrict__ out) {
  int br = blockIdx.z;
  const u16* A = br ? Apts : Aimg;
  const u16* B = br ? Bpts : Bimg;
  const float* bias = br ? biasPts : biasImg;

  // bijective XCD chunk swizzle: 4096 wgs, 8 XCDs, 512 per XCD
  int s = blockIdx.x;
  int w = (s & 7) * 512 + (s >> 3);
  int rt = w & 3;                      // row tile 0..3 (consecutive on one XCD)
  int ct = w >> 2;                     // col tile 0..1023
  int n = ct >> 9;                     // sample
  int colbase = (ct & 511) * 128;      // hw base within sample
  const u16* Bn = B + ((long)n * 65536) * 512;

  __shared__ u16 As[4][128 * 32];      // 32 KiB
  __shared__ u16 Bs[4][128 * 32];      // 32 KiB

  int t = threadIdx.x;
  int wave = t >> 6, lane = t & 63;
  int wr = wave >> 1, wc = wave & 1;
  int lrow = lane & 15;
  int q = lane >> 4;                   // k-chunk 0..3 (16B chunks)

  f32x4 acc[4][4] = {};

#define STAGE(buf, kk)                                                        \
  {                                                                           \
    _Pragma("unroll") for (int i = 0; i < 2; ++i) {                           \
      int slot = t + i * 256;                                                 \
      int row = slot >> 2, kp = slot & 3;                                     \
      int sw = (row >> 1) & 3;                                                \
      GLOAD16(A + ((long)(rt * 128 + row) * 512 + (kk) + ((kp ^ sw) * 8)),    \
              &As[buf][slot * 8]);                                            \
      GLOAD16(Bn + ((long)(colbase + row) * 512 + (kk) + ((kp ^ sw) * 8)),    \
              &Bs[buf][slot * 8]);                                            \
    }                                                                         \
  }

  // prologue: stages 0,1,2 in flight (12 loads); retire stage 0 -> vmcnt(8)
  STAGE(0, 0);
  STAGE(1, 32);
  STAGE(2, 64);
  asm volatile("s_waitcnt vmcnt(8)" ::: "memory");
  __builtin_amdgcn_s_barrier();

  for (int kt = 0; kt < 16; ++kt) {
    int cur = kt & 3;
    s8frag a[4], b[4];
#pragma unroll
    for (int m = 0; m < 4; ++m) {
      int r = wr * 64 + m * 16 + lrow;
      a[m] = *(const s8frag*)&As[cur][r * 32 + ((q ^ ((r >> 1) & 3)) * 8)];
    }
#pragma unroll
    for (int nn = 0; nn < 4; ++nn) {
      int r = wc * 64 + nn * 16 + lrow;
      b[nn] = *(const s8frag*)&Bs[cur][r * 32 + ((q ^ ((r >> 1) & 3)) * 8)];
    }
    if (kt < 13) STAGE((kt + 3) & 3, (kt + 3) * 32);  // 2-step-slack prefetch
    __builtin_amdgcn_s_setprio(1);
#pragma unroll
    for (int m = 0; m < 4; ++m)
#pragma unroll
      for (int nn = 0; nn < 4; ++nn)
        acc[m][nn] =
            __builtin_amdgcn_mfma_f32_16x16x32_bf16(a[m], b[nn], acc[m][nn], 0, 0, 0);
    __builtin_amdgcn_s_setprio(0);
    if (kt < 15) {
      // ensure stage kt+1 (issued at step kt-2) is complete before flipping
      if (kt <= 12)
        asm volatile("s_waitcnt vmcnt(8)" ::: "memory");
      else if (kt == 13)
        asm volatile("s_waitcnt vmcnt(4)" ::: "memory");
      else
        asm volatile("s_waitcnt vmcnt(0)" ::: "memory");
      __builtin_amdgcn_s_barrier();
    }
  }
#undef STAGE

  // epilogue: bias + relu, write fp32 NCHW with channel offset br*512
  long outbase = ((long)n * 1024 + br * 512) * 65536;
#pragma unroll
  for (int m = 0; m < 4; ++m) {
    int o0 = rt * 128 + wr * 64 + m * 16 + (lane >> 4) * 4;
#pragma unroll
    for (int nn = 0; nn < 4; ++nn) {
      int hw = colbase + wc * 64 + nn * 16 + (lane & 15);
#pragma unroll
      for (int j = 0; j < 4; ++j) {
        int o = o0 + j;
        float v = acc[m][nn][j] + bias[o];
        v = v > 0.f ? v : 0.f;
        out[outbase + (long)o * 65536 + hw] = v;
      }
    }
  }
}

// ---------------------------------------------------------------------------
extern "C" void kernel_launch(void* const* d_in, const int* in_sizes, int n_in,
                              void* d_out, int out_size, void* d_ws,
                              size_t ws_size, hipStream_t stream) {
  (void)in_sizes; (void)n_in; (void)out_size; (void)ws_size;
  const float* f0 = (const float*)d_in[0];
  const float* f1 = (const float*)d_in[1];
  const float* f2 = (const float*)d_in[2];
  const float* f3 = (const float*)d_in[3];
  const float* f4 = (const float*)d_in[4];
  const float* pts = (const float*)d_in[5];
  const float* img_w = (const float*)d_in[6];
  const float* img_b = (const float*)d_in[7];
  const float* img_gamma = (const float*)d_in[8];
  const float* img_beta = (const float*)d_in[9];
  const float* img_mean = (const float*)d_in[10];
  const float* img_var = (const float*)d_in[11];
  const float* pts_w = (const float*)d_in[12];
  const float* pts_b = (const float*)d_in[13];
  const float* pts_gamma = (const float*)d_in[14];
  const float* pts_beta = (const float*)d_in[15];
  const float* pts_mean = (const float*)d_in[16];
  const float* pts_var = (const float*)d_in[17];

  char* ws = (char*)d_ws;
  u16* wA_img = (u16*)ws;                          // 512 KiB
  u16* wA_pts = wA_img + 512 * 512;                // 512 KiB
  float* bias_img = (float*)(ws + (1u << 20));
  float* bias_pts = bias_img + 512;
  u16* Bimg = (u16*)(ws + (2u << 20));             // 128 MiB
  u16* Bpts = Bimg + (size_t)2 * 65536 * 512;      // 128 MiB

  prep_w<<<2048, 256, 0, stream>>>(img_w, img_b, img_gamma, img_beta, img_mean,
                                   img_var, pts_w, pts_b, pts_gamma, pts_beta,
                                   pts_mean, pts_var, wA_img, bias_img, wA_pts,
                                   bias_pts);
  build_img_t<<<dim3(4, 256, 16), 256, 0, stream>>>(f0, f1, f2, f3, f4, Bimg);
  build_pts_t<<<dim3(4, 256, 16), 256, 0, stream>>>(pts, Bpts);
  gemm_fused<<<dim3(4096, 1, 2), 256, 0, stream>>>(
      wA_img, wA_pts, Bimg, Bpts, bias_img, bias_pts, (float*)d_out);
}

// Round 9
// 485.139 us; speedup vs baseline: 2.0901x; 1.1181x over previous
//
#include <hip/hip_runtime.h>

typedef unsigned short u16;
typedef __attribute__((ext_vector_type(8))) short s8frag;   // 8 bf16 (4 VGPRs)
typedef __attribute__((ext_vector_type(4))) float f32x4;    // MFMA accumulator

#define GLOAD16(gp, lp)                                                        \
  __builtin_amdgcn_global_load_lds(                                            \
      (const __attribute__((address_space(1))) void*)(gp),                     \
      (__attribute__((address_space(3))) void*)(lp), 16, 0, 0)

__device__ __forceinline__ u16 f2bf(float x) {
  unsigned int u = __float_as_uint(x);
  unsigned int r = (u + 0x7fffu + ((u >> 16) & 1u)) >> 16;  // RNE
  return (u16)r;
}

// ---------------------------------------------------------------------------
// Kernel 1: fold BN into 1x1-conv weights (both branches in one launch).
// ---------------------------------------------------------------------------
__global__ __launch_bounds__(256) void prep_w(
    const float* __restrict__ wi, const float* __restrict__ bi,
    const float* __restrict__ gi, const float* __restrict__ bei,
    const float* __restrict__ mi, const float* __restrict__ vi,
    const float* __restrict__ wp, const float* __restrict__ bp,
    const float* __restrict__ gp, const float* __restrict__ bep,
    const float* __restrict__ mp, const float* __restrict__ vp,
    u16* __restrict__ wout_i, float* __restrict__ bias_i,
    u16* __restrict__ wout_p, float* __restrict__ bias_p) {
  int gidx = blockIdx.x * 256 + threadIdx.x;  // 0 .. 2*512*512-1
  int branch = gidx >> 18;
  int idx = gidx & ((1 << 18) - 1);
  int o = idx >> 9, c = idx & 511;
  const float* w = branch ? wp : wi;
  const float* b = branch ? bp : bi;
  const float* g = branch ? gp : gi;
  const float* be = branch ? bep : bei;
  const float* mn = branch ? mp : mi;
  const float* vr = branch ? vp : vi;
  u16* wo = branch ? wout_p : wout_i;
  float* bo = branch ? bias_p : bias_i;
  float scale = g[o] * rsqrtf(vr[o] + 1e-5f);
  wo[idx] = f2bf(w[idx] * scale);
  if (c == 0) bo[o] = scale * (b[o] - mn[o]) + be[o];
}

// ---------------------------------------------------------------------------
// Kernel 2 (merged builders): z<16 = img multi-level sum (upsample-by-(n+1)
// for lvl>0, edge-pad to 256); z>=16 = pts transpose (float4 loads).
// Both write TRANSPOSED bf16: dst[n][hw][c] (c contiguous).
// Bodies verbatim from the round-1/round-3 passing kernels.
// ---------------------------------------------------------------------------
__global__ __launch_bounds__(256) void build_b(
    const float* __restrict__ f0, const float* __restrict__ f1,
    const float* __restrict__ f2, const float* __restrict__ f3,
    const float* __restrict__ f4, const float* __restrict__ pts,
    u16* __restrict__ Bimg, u16* __restrict__ Bpts) {
  __shared__ float tile[64][65];
  int t = threadIdx.x;
  int wblk = blockIdx.x;          // 0..3
  int h = blockIdx.y;             // 0..255
  int z = blockIdx.z;             // 0..31
  bool is_img = z < 16;
  int zz = is_img ? z : z - 16;
  int n = zz >> 3;                // 0..1
  int cblk = zz & 7;              // 0..7
  int cbase = cblk * 64;

  if (is_img) {
    int wl = t & 63, w = wblk * 64 + wl;
    const float* feats[5] = {f0, f1, f2, f3, f4};
    const int S[5] = {128, 64, 32, 16, 8};
    int off[5];
#pragma unroll
    for (int l = 0; l < 5; ++l) {
      int s = S[l];
      int scale = (n == 1 && l > 0) ? 2 : 1;
      int u = s * scale, pad = (256 - u) >> 1;
      int ih = h - pad; ih = ih < 0 ? 0 : (ih > u - 1 ? u - 1 : ih); ih /= scale;
      int iw = w - pad; iw = iw < 0 ? 0 : (iw > u - 1 ? u - 1 : iw); iw /= scale;
      off[l] = ih * s + iw;
    }
    for (int cs = 0; cs < 16; ++cs) {
      int cl = cs * 4 + (t >> 6);
      int c = cbase + cl;
      float acc = 0.f;
#pragma unroll
      for (int l = 0; l < 5; ++l) {
        int s = S[l];
        acc += feats[l][(long)(n * 512 + c) * s * s + off[l]];
      }
      tile[cl][wl] = acc;
    }
  } else {
    int wq = t & 15;     // w-quad within 64
    int cl0 = t >> 4;    // 0..15
#pragma unroll
    for (int j = 0; j < 4; ++j) {
      int cl = cl0 + j * 16;
      int c = cbase + cl;
      float4 v = *(const float4*)&pts[((long)(n * 512 + c) * 256 + h) * 256 +
                                      wblk * 64 + wq * 4];
      tile[cl][wq * 4 + 0] = v.x;
      tile[cl][wq * 4 + 1] = v.y;
      tile[cl][wq * 4 + 2] = v.z;
      tile[cl][wq * 4 + 3] = v.w;
    }
  }
  __syncthreads();

  u16* dst = is_img ? Bimg : Bpts;
  long hwb = (long)h * 256 + wblk * 64;
#pragma unroll
  for (int half = 0; half < 2; ++half) {
    int c0 = (t & 7) * 8;
    int wl2 = half * 32 + (t >> 3);
    u16 p[8];
#pragma unroll
    for (int j = 0; j < 8; ++j) p[j] = f2bf(tile[c0 + j][wl2]);
    long di = ((long)n * 65536 + hwb + wl2) * 512 + cbase + c0;
    *(uint4*)(dst + di) = *(const uint4*)p;
  }
}

// ---------------------------------------------------------------------------
// Kernel 3: bf16 MFMA GEMM, 128x128 tile, BK=32, 4 waves, acc 4x4 --
// PHASE-SPLIT schedule (T3+T4 mechanism): each K-step = 2 phases, each
// phase = {ds_read frag subtile || issue half of stage kt+2} -> MFMA
// half-cluster (setprio) -> barrier. Counted vmcnt(4) once per step
// (never 0 in steady state). Ring-3 LDS (48 KiB -> 3 blocks/CU).
// Fragment math + LDS XOR swizzle identical to the round-5 passing kernel.
// XCD-chunked swizzle: 4 rt of one col-tile back-to-back on one XCD.
// ---------------------------------------------------------------------------
__global__ __launch_bounds__(256) void gemm_fused(
    const u16* __restrict__ Aimg, const u16* __restrict__ Apts,
    const u16* __restrict__ Bimg, const u16* __restrict__ Bpts,
    const float* __restrict__ biasImg, const float* __restrict__ biasPts,
    float* __restrict__ out) {
  int br = blockIdx.z;
  const u16* A = br ? Apts : Aimg;
  const u16* B = br ? Bpts : Bimg;
  const float* bias = br ? biasPts : biasImg;

  // bijective XCD chunk swizzle: 4096 wgs, 8 XCDs, 512 per XCD
  int s = blockIdx.x;
  int w = (s & 7) * 512 + (s >> 3);
  int rt = w & 3;                      // row tile 0..3 (consecutive on one XCD)
  int ct = w >> 2;                     // col tile 0..1023
  int n = ct >> 9;                     // sample
  int colbase = (ct & 511) * 128;      // hw base within sample
  const u16* Bn = B + ((long)n * 65536) * 512;

  __shared__ u16 As[3][128 * 32];      // 24 KiB
  __shared__ u16 Bs[3][128 * 32];      // 24 KiB

  int t = threadIdx.x;
  int wave = t >> 6, lane = t & 63;
  int wr = wave >> 1, wc = wave & 1;
  int lrow = lane & 15;
  int q = lane >> 4;                   // k-chunk 0..3 (16B chunks)

  f32x4 acc[4][4] = {};

#define STAGE_A(buf, kk)                                                      \
  {                                                                           \
    _Pragma("unroll") for (int i = 0; i < 2; ++i) {                           \
      int slot = t + i * 256;                                                 \
      int row = slot >> 2, kp = slot & 3;                                     \
      int sw = (row >> 1) & 3;                                                \
      GLOAD16(A + ((long)(rt * 128 + row) * 512 + (kk) + ((kp ^ sw) * 8)),    \
              &As[buf][slot * 8]);                                            \
    }                                                                         \
  }
#define STAGE_B(buf, kk)                                                      \
  {                                                                           \
    _Pragma("unroll") for (int i = 0; i < 2; ++i) {                           \
      int slot = t + i * 256;                                                 \
      int row = slot >> 2, kp = slot & 3;                                     \
      int sw = (row >> 1) & 3;                                                \
      GLOAD16(Bn + ((long)(colbase + row) * 512 + (kk) + ((kp ^ sw) * 8)),    \
              &Bs[buf][slot * 8]);                                            \
    }                                                                         \
  }

  // prologue: stages 0,1 fully in flight (8 loads); retire stage 0
  STAGE_A(0, 0);
  STAGE_B(0, 0);
  STAGE_A(1, 32);
  STAGE_B(1, 32);
  asm volatile("s_waitcnt vmcnt(4)" ::: "memory");
  __builtin_amdgcn_s_barrier();

  for (int kt = 0; kt < 16; ++kt) {
    int cur = kt % 3;
    int nb = (kt + 2) % 3;
    // ---- phase 1: read a0,a1,b0..3; issue A-half of stage kt+2; MFMA m=0,1
    s8frag a0, a1, b[4];
    {
      int r0 = wr * 64 + 0 * 16 + lrow;
      a0 = *(const s8frag*)&As[cur][r0 * 32 + ((q ^ ((r0 >> 1) & 3)) * 8)];
      int r1 = wr * 64 + 1 * 16 + lrow;
      a1 = *(const s8frag*)&As[cur][r1 * 32 + ((q ^ ((r1 >> 1) & 3)) * 8)];
#pragma unroll
      for (int nn = 0; nn < 4; ++nn) {
        int r = wc * 64 + nn * 16 + lrow;
        b[nn] = *(const s8frag*)&Bs[cur][r * 32 + ((q ^ ((r >> 1) & 3)) * 8)];
      }
    }
    if (kt < 14) STAGE_A(nb, (kt + 2) * 32);
    __builtin_amdgcn_s_setprio(1);
#pragma unroll
    for (int nn = 0; nn < 4; ++nn)
      acc[0][nn] = __builtin_amdgcn_mfma_f32_16x16x32_bf16(a0, b[nn], acc[0][nn], 0, 0, 0);
#pragma unroll
    for (int nn = 0; nn < 4; ++nn)
      acc[1][nn] = __builtin_amdgcn_mfma_f32_16x16x32_bf16(a1, b[nn], acc[1][nn], 0, 0, 0);
    __builtin_amdgcn_s_setprio(0);
    __builtin_amdgcn_s_barrier();

    // ---- phase 2: read a2,a3; issue B-half of stage kt+2; MFMA m=2,3
    s8frag a2, a3;
    {
      int r2 = wr * 64 + 2 * 16 + lrow;
      a2 = *(const s8frag*)&As[cur][r2 * 32 + ((q ^ ((r2 >> 1) & 3)) * 8)];
      int r3 = wr * 64 + 3 * 16 + lrow;
      a3 = *(const s8frag*)&As[cur][r3 * 32 + ((q ^ ((r3 >> 1) & 3)) * 8)];
    }
    if (kt < 14) STAGE_B(nb, (kt + 2) * 32);
    __builtin_amdgcn_s_setprio(1);
#pragma unroll
    for (int nn = 0; nn < 4; ++nn)
      acc[2][nn] = __builtin_amdgcn_mfma_f32_16x16x32_bf16(a2, b[nn], acc[2][nn], 0, 0, 0);
#pragma unroll
    for (int nn = 0; nn < 4; ++nn)
      acc[3][nn] = __builtin_amdgcn_mfma_f32_16x16x32_bf16(a3, b[nn], acc[3][nn], 0, 0, 0);
    __builtin_amdgcn_s_setprio(0);
    if (kt < 15) {
      // steady state: stages kt+1 (4 loads) + kt+2 (4) outstanding;
      // vmcnt(4) retires exactly stage kt+1. Tail: kt=14 drains stage 15.
      if (kt < 14)
        asm volatile("s_waitcnt vmcnt(4)" ::: "memory");
      else
        asm volatile("s_waitcnt vmcnt(0)" ::: "memory");
      __builtin_amdgcn_s_barrier();
    }
  }
#undef STAGE_A
#undef STAGE_B

  // epilogue: bias + relu, write fp32 NCHW with channel offset br*512
  long outbase = ((long)n * 1024 + br * 512) * 65536;
#pragma unroll
  for (int m = 0; m < 4; ++m) {
    int o0 = rt * 128 + wr * 64 + m * 16 + (lane >> 4) * 4;
#pragma unroll
    for (int nn = 0; nn < 4; ++nn) {
      int hw = colbase + wc * 64 + nn * 16 + (lane & 15);
#pragma unroll
      for (int j = 0; j < 4; ++j) {
        int o = o0 + j;
        float v = acc[m][nn][j] + bias[o];
        v = v > 0.f ? v : 0.f;
        out[outbase + (long)o * 65536 + hw] = v;
      }
    }
  }
}

// ---------------------------------------------------------------------------
extern "C" void kernel_launch(void* const* d_in, const int* in_sizes, int n_in,
                              void* d_out, int out_size, void* d_ws,
                              size_t ws_size, hipStream_t stream) {
  (void)in_sizes; (void)n_in; (void)out_size; (void)ws_size;
  const float* f0 = (const float*)d_in[0];
  const float* f1 = (const float*)d_in[1];
  const float* f2 = (const float*)d_in[2];
  const float* f3 = (const float*)d_in[3];
  const float* f4 = (const float*)d_in[4];
  const float* pts = (const float*)d_in[5];
  const float* img_w = (const float*)d_in[6];
  const float* img_b = (const float*)d_in[7];
  const float* img_gamma = (const float*)d_in[8];
  const float* img_beta = (const float*)d_in[9];
  const float* img_mean = (const float*)d_in[10];
  const float* img_var = (const float*)d_in[11];
  const float* pts_w = (const float*)d_in[12];
  const float* pts_b = (const float*)d_in[13];
  const float* pts_gamma = (const float*)d_in[14];
  const float* pts_beta = (const float*)d_in[15];
  const float* pts_mean = (const float*)d_in[16];
  const float* pts_var = (const float*)d_in[17];

  char* ws = (char*)d_ws;
  u16* wA_img = (u16*)ws;                          // 512 KiB
  u16* wA_pts = wA_img + 512 * 512;                // 512 KiB
  float* bias_img = (float*)(ws + (1u << 20));
  float* bias_pts = bias_img + 512;
  u16* Bimg = (u16*)(ws + (2u << 20));             // 128 MiB
  u16* Bpts = Bimg + (size_t)2 * 65536 * 512;      // 128 MiB

  prep_w<<<2048, 256, 0, stream>>>(img_w, img_b, img_gamma, img_beta, img_mean,
                                   img_var, pts_w, pts_b, pts_gamma, pts_beta,
                                   pts_mean, pts_var, wA_img, bias_img, wA_pts,
                                   bias_pts);
  build_b<<<dim3(4, 256, 32), 256, 0, stream>>>(f0, f1, f2, f3, f4, pts, Bimg,
                                                Bpts);
  gemm_fused<<<dim3(4096, 1, 2), 256, 0, stream>>>(
      wA_img, wA_pts, Bimg, Bpts, bias_img, bias_pts, (float*)d_out);
}